// Round 8
// baseline (69.593 us; speedup 1.0000x reference)
//
#include <hip/hip_runtime.h>
#include <hip/hip_bf16.h>
#include <stdint.h>

// AutoregressiveDense: B=8192, D=1024, STRIDE=16, OUT=64, L=64
#define BROWS 8192
#define DDIM  1024
#define LDIM  64
#define ODIM  64
#define NDIM  4096
#define KSTRIDE 16

typedef __attribute__((ext_vector_type(8))) short bf16x8;           // MFMA A/B frag
typedef __attribute__((ext_vector_type(4))) float f32x4;            // MFMA C/D frag
typedef __attribute__((ext_vector_type(8))) unsigned short u16x8;   // 16B bf16 store

static __device__ __forceinline__ unsigned short f2bf(float f) {
    union { float f; uint32_t u; } v; v.f = f;
    uint32_t r = 0x7FFFu + ((v.u >> 16) & 1u);
    return (unsigned short)((v.u + r) >> 16);
}

static __device__ __forceinline__ void async16(const void* g, void* l) {
    __builtin_amdgcn_global_load_lds(
        (const __attribute__((address_space(1))) void*)g,
        (__attribute__((address_space(3))) void*)l, 16, 0, 0);
}

// ---------- merged prep: blocks [0,1024) build masked W' (B^T bf16), blocks [1024,5120) convert x ----------
__global__ __launch_bounds__(256) void prep_kernel(const float* __restrict__ x,
                                                   const float* __restrict__ W,
                                                   unsigned short* __restrict__ xb,
                                                   unsigned short* __restrict__ wbt) {
    const int bid = blockIdx.x;
    if (bid < 1024) {
        // W [L][D][O] f32 -> masked bf16 W' [N=l*64+o][K=d], zero for d >= l*16
        __shared__ float tile[64][65];
        const int l  = bid >> 4;
        const int d0 = (bid & 15) << 6;
        const int t  = threadIdx.x;
        {
            const int dd = t >> 2;
            const int o4 = (t & 3) << 4;
            const float* src = W + ((size_t)((l << 10) + d0 + dd) << 6) + o4;
            #pragma unroll
            for (int j = 0; j < 4; ++j) {
                float4 v = reinterpret_cast<const float4*>(src)[j];
                tile[dd][o4 + 4 * j + 0] = v.x;
                tile[dd][o4 + 4 * j + 1] = v.y;
                tile[dd][o4 + 4 * j + 2] = v.z;
                tile[dd][o4 + 4 * j + 3] = v.w;
            }
        }
        __syncthreads();
        {
            const int o    = t >> 2;
            const int dloc = (t & 3) << 4;
            const int kmax = l * KSTRIDE;
            unsigned short* dst = wbt + ((size_t)((l << 6) + o) << 10) + d0 + dloc;
            u16x8 r0, r1;
            #pragma unroll
            for (int j = 0; j < 8; ++j) {
                int da = d0 + dloc + j;
                int db = da + 8;
                r0[j] = (da < kmax) ? f2bf(tile[dloc + j][o])     : (unsigned short)0;
                r1[j] = (db < kmax) ? f2bf(tile[dloc + 8 + j][o]) : (unsigned short)0;
            }
            *reinterpret_cast<u16x8*>(dst)     = r0;
            *reinterpret_cast<u16x8*>(dst + 8) = r1;
        }
    } else {
        int i = (bid - 1024) * 256 + threadIdx.x;
        const float4* xf = reinterpret_cast<const float4*>(x);
        float4 v0 = xf[2 * i];
        float4 v1 = xf[2 * i + 1];
        u16x8 r;
        r[0] = f2bf(v0.x); r[1] = f2bf(v0.y); r[2] = f2bf(v0.z); r[3] = f2bf(v0.w);
        r[4] = f2bf(v1.x); r[5] = f2bf(v1.y); r[6] = f2bf(v1.z); r[7] = f2bf(v1.w);
        reinterpret_cast<u16x8*>(xb)[i] = r;
    }
}

// ---------- main GEMM: 256x128 tile, BK=32, 8 waves (4Mx2N, wave tile 64x64) ----------
// r7 analysis: 2109 cyc/block-step measured vs LDS 1035 + MFMA 621 serial => the ds_read
// burst and the MFMA cluster never overlap (first MFMA waits lgkm on this step's reads;
// resident blocks phase-lock). Fix: REGISTER FRAG DOUBLE-BUFFER — iter t reads tile t+1's
// fragments into the alternate set while the MFMAs run on tile t's resident set (no lgkm
// dependency). lgkmcnt(0) AFTER the MFMAs (served by then, ~free) closes the cross-wave
// WAR before the next barrier. vmcnt(3) now guarantees tile t+1 landed (stage t+3 issues
// after it: outstanding = t+2,t+3). 3 LDS bufs x 24KB = 72KB. VGPR ~160-200 -> 1 block/CU;
// overlap is within-wave so cross-block TLP no longer needed.
#define MMQ(A, B) \
    _Pragma("unroll") \
    for (int m = 0; m < 4; ++m) \
    _Pragma("unroll") \
    for (int n = 0; n < 4; ++n) \
        acc[m][n] = __builtin_amdgcn_mfma_f32_16x16x32_bf16(A[m], B[n], acc[m][n], 0, 0, 0);

#define READF(T, A, B) do { \
    const char* pb_ = lds + ((T) % 3) * 24576; \
    _Pragma("unroll") \
    for (int m = 0; m < 4; ++m) A[m] = *reinterpret_cast<const bf16x8*>(pb_ + aoff + m * 1024); \
    _Pragma("unroll") \
    for (int n = 0; n < 4; ++n) B[n] = *reinterpret_cast<const bf16x8*>(pb_ + boff + n * 1024); \
} while (0)

// One pipeline phase: compute tile T from (Acur,Bcur); prefetch tile T+1 frags into (Anxt,Bnxt).
#define PHASE(T, Acur, Bcur, Anxt, Bnxt) \
    asm volatile("s_waitcnt vmcnt(3)" ::: "memory");   /* tile T+1 landed; T+2 in flight */ \
    __builtin_amdgcn_sched_barrier(0); \
    __builtin_amdgcn_s_barrier();                      /* raw barrier: no vmcnt(0) drain */ \
    stage((T) + 3);                                    /* buf[T%3]: readers drained last iter */ \
    READF((T) + 1, Anxt, Bnxt);                        /* LDS reads overlap MFMAs below */ \
    __builtin_amdgcn_sched_barrier(0); \
    __builtin_amdgcn_s_setprio(1); \
    MMQ(Acur, Bcur); \
    __builtin_amdgcn_s_setprio(0); \
    asm volatile("s_waitcnt lgkmcnt(0)" ::: "memory"); /* reads served; WAR-safe for next barrier */

__global__ __launch_bounds__(512)
__attribute__((amdgpu_waves_per_eu(2)))
void ar_gemm_kernel(const unsigned short* __restrict__ xb,
                    const unsigned short* __restrict__ wbt,
                    const float* __restrict__ bias,
                    float* __restrict__ out) {
    __shared__ char lds[73728];   // buf p at p*24576: A[256][64B] at +0, B[128][64B] at +16384

    const int s  = blockIdx.x >> 8;            // 4 supertiles of 256 blocks (one generation each)
    const int i  = blockIdx.x & 255;
    const int bm = ((s & 1) << 4) + (i & 15);          // 0..31 (tiles of 256 rows)
    const int bn = ((s < 2) ? 16 : 0) + 15 - (i >> 4); // heavy bn (16..31) first, big nkt first
    const int tid  = threadIdx.x;
    const int lane = tid & 63;
    const int wid  = tid >> 6;
    const int wm   = wid >> 1;                 // 4 M-waves x 2 N-waves, wave tile 64x64
    const int wn   = wid & 1;

    const int nkt = bn + 1;                    // K-tiles of 32

    // staging: thread t -> row t>>2, 16B chunk (t&3) of the 64B k-row; LDS linear t*16
    const int cb = (tid & 3) << 4;
    const char* gA = (const char*)xb  + ((size_t)((bm << 8) + (tid >> 2)) << 11) + cb;
    const char* gB = (const char*)wbt + ((size_t)((bn << 7) + (tid >> 2)) << 11) + cb;

    // fragment read offsets (bytes): row = (lane&15), k-granule by lane>>4 (r1-proven layout)
    const int aoff = ((wm << 6) + (lane & 15)) * 64 + ((lane >> 4) << 4);
    const int boff = 16384 + ((wn << 6) + (lane & 15)) * 64 + ((lane >> 4) << 4);

    f32x4 acc[4][4];
    #pragma unroll
    for (int m = 0; m < 4; ++m)
        #pragma unroll
        for (int n = 0; n < 4; ++n)
            acc[m][n] = (f32x4)(0.f);

    bf16x8 aA[4], bA[4], aB[4], bB[4];

    // stage K-tile t into buffer t%3 (3 asyncs/thread). Clamp source for t>=nkt (dest unused).
    auto stage = [&](int t) {
        const int kb = (t < nkt ? t : nkt - 1) << 6;
        char* l = lds + (t % 3) * 24576 + tid * 16;
        async16(gA + kb, l);
        async16(gA + ((size_t)128 << 11) + kb, l + 8192);
        async16(gB + kb, l + 16384);
    };

    stage(0); stage(1); stage(2);                      // 9 loads in flight
    asm volatile("s_waitcnt vmcnt(6)" ::: "memory");   // tile0 landed
    __builtin_amdgcn_s_barrier();                      // all waves' tile0 visible
    READF(0, aA, bA);                                  // pre-read tile0 frags
    asm volatile("s_waitcnt lgkmcnt(0)" ::: "memory"); // drained before loop's first barrier

    int t = 0;
    while (true) {
        PHASE(t, aA, bA, aB, bB);
        if (++t >= nkt) break;
        PHASE(t, aB, bB, aA, bA);
        if (++t >= nkt) break;
    }
    asm volatile("s_waitcnt vmcnt(0)" ::: "memory");   // drain clamped tail stages

    // epilogue: C/D layout col=lane&15, row=(lane>>4)*4+j; add bias in f32
    const int crow = (bm << 8) + (wm << 6) + ((lane >> 4) << 2);
    const int ccol = (bn << 7) + (wn << 6) + (lane & 15);
    float bv[4];
    #pragma unroll
    for (int n = 0; n < 4; ++n) bv[n] = bias[ccol + n * 16];
    #pragma unroll
    for (int m = 0; m < 4; ++m)
        #pragma unroll
        for (int n = 0; n < 4; ++n)
            #pragma unroll
            for (int j = 0; j < 4; ++j)
                out[(size_t)(crow + m * 16 + j) * NDIM + ccol + n * 16] = acc[m][n][j] + bv[n];
}

// ---------- fallback: naive f32 (used only if workspace too small) ----------
__global__ __launch_bounds__(256) void naive_kernel(const float* __restrict__ x,
                                                    const float* __restrict__ W,
                                                    const float* __restrict__ bias,
                                                    float* __restrict__ out) {
    size_t idx = (size_t)blockIdx.x * 256 + threadIdx.x;
    if (idx >= (size_t)BROWS * NDIM) return;
    int m = (int)(idx >> 12);
    int n = (int)(idx & 4095);
    int l = n >> 6;
    int o = n & 63;
    int kmax = l * KSTRIDE;
    float s = bias[n];
    const float* xr = x + (size_t)m * DDIM;
    const float* wp = W + ((size_t)l << 16) + o;
    for (int d = 0; d < kmax; ++d) s += xr[d] * wp[(size_t)d << 6];
    out[idx] = s;
}

extern "C" void kernel_launch(void* const* d_in, const int* in_sizes, int n_in,
                              void* d_out, int out_size, void* d_ws, size_t ws_size,
                              hipStream_t stream) {
    const float* x = (const float*)d_in[0];
    const float* W = (const float*)d_in[1];
    const float* b = (const float*)d_in[2];
    float* out = (float*)d_out;

    const size_t need = ((size_t)BROWS * DDIM + (size_t)NDIM * DDIM) * sizeof(unsigned short);
    if (ws_size < need) {
        int total = BROWS * NDIM;
        naive_kernel<<<(total + 255) / 256, 256, 0, stream>>>(x, W, b, out);
        return;
    }
    unsigned short* xbuf = (unsigned short*)d_ws;             // bf16 x  [8192][1024]
    unsigned short* wbt  = xbuf + (size_t)BROWS * DDIM;       // bf16 W' [4096][1024]

    prep_kernel<<<5120, 256, 0, stream>>>(x, W, xbuf, wbt);
    ar_gemm_kernel<<<1024, 512, 0, stream>>>(xbuf, wbt, b, out);
}